// Round 7
// baseline (459.876 us; speedup 1.0000x reference)
//
#include <hip/hip_runtime.h>

// AVWGCN: out[b,n,o] = sum_k sum_i xg_k[b,n,i] * w[k,i,o] + bias[o]
//   xg0 = x, xg1 = S@x, xg2 = 2*S@(S@x) - x   (S = softmax(relu(adj@emb), rows))
// Algebra: never form T2; fold "2*" and "-x" into Wcat = [w0-w2 | w1 | 2*w2].
// GEMM: round-3 schedule (best measured ~136 µs). NEW: mix is fused into
// GEMM2's epilogue — a 256-wide bc tile = 4 whole batches x 64 channels, and
// each wave's 64-col slice is exactly one batch, so the wave's accumulators
// hold the complete XG2 contribution for (b, 128 n-rows). XG2 is never
// written to HBM (saves 64 MB round-trip + the mix dispatch).

typedef __bf16 bf16;
typedef __bf16 bf16x8 __attribute__((ext_vector_type(8)));
typedef float f32x4 __attribute__((ext_vector_type(4)));

__device__ __forceinline__ void async_lds16(const void* g, void* l) {
  __builtin_amdgcn_global_load_lds((const __attribute__((address_space(1))) void*)g,
                                   (__attribute__((address_space(3))) void*)l, 16, 0, 0);
}

#define FENCE() asm volatile("" ::: "memory")
#define BAR()                          \
  do {                                 \
    FENCE();                           \
    __builtin_amdgcn_s_barrier();      \
    FENCE();                           \
  } while (0)
#define WAIT_VM(n) asm volatile("s_waitcnt vmcnt(" #n ")" ::: "memory")

// ---- Wcat[o][kk] bf16, kk in [0,192): [w0-w2 | w1 | 2*w2] transposed to o-rows ----
__global__ __launch_bounds__(256) void build_wcat_k(const float* __restrict__ w, bf16* __restrict__ Wc) {
  int idx = blockIdx.x * 256 + threadIdx.x;
  if (idx >= 64 * 192) return;
  int o = idx / 192, kk = idx - o * 192;
  int k = kk >> 6, i = kk & 63;
  float v;
  if (k == 0)      v = w[i * 64 + o] - w[2 * 4096 + i * 64 + o];
  else if (k == 1) v = w[4096 + i * 64 + o];
  else             v = 2.f * w[2 * 4096 + i * 64 + o];
  Wc[idx] = (bf16)v;
}

// ---- S[n][m] = softmax(relu(adj@emb)) rows, stored bf16. 8 rows per block. ----
__global__ __launch_bounds__(256) void supports_k(const float* __restrict__ adj,
                                                  const float* __restrict__ emb,
                                                  bf16* __restrict__ S) {
  __shared__ float slog[8][4096];  // 128 KiB logit stash
  __shared__ float sadj[8][16];
  __shared__ float swred[4][8];
  const int tid = threadIdx.x;
  const int lane = tid & 63, wv = tid >> 6;
  const int n0 = blockIdx.x * 8;
  if (tid < 128) sadj[tid >> 4][tid & 15] = adj[n0 * 16 + tid];
  __syncthreads();

  float mx[8];
  #pragma unroll
  for (int r = 0; r < 8; ++r) mx[r] = 0.f;  // relu => max >= 0

  for (int it = 0; it < 16; ++it) {
    const int j = it * 256 + tid;
    float e[16];
    #pragma unroll
    for (int k = 0; k < 16; ++k) e[k] = emb[k * 4096 + j];
    #pragma unroll
    for (int r = 0; r < 8; ++r) {
      float v = 0.f;
      #pragma unroll
      for (int k = 0; k < 16; ++k) v = fmaf(sadj[r][k], e[k], v);
      v = fmaxf(v, 0.f);
      slog[r][j] = v;
      mx[r] = fmaxf(mx[r], v);
    }
  }
  #pragma unroll
  for (int r = 0; r < 8; ++r) {
    #pragma unroll
    for (int off = 32; off > 0; off >>= 1) mx[r] = fmaxf(mx[r], __shfl_xor(mx[r], off, 64));
  }
  if (lane == 0) {
    #pragma unroll
    for (int r = 0; r < 8; ++r) swred[wv][r] = mx[r];
  }
  __syncthreads();
  #pragma unroll
  for (int r = 0; r < 8; ++r)
    mx[r] = fmaxf(fmaxf(swred[0][r], swred[1][r]), fmaxf(swred[2][r], swred[3][r]));

  float sm[8];
  #pragma unroll
  for (int r = 0; r < 8; ++r) sm[r] = 0.f;
  for (int it = 0; it < 16; ++it) {
    const int j = it * 256 + tid;
    #pragma unroll
    for (int r = 0; r < 8; ++r) {
      float ev = __expf(slog[r][j] - mx[r]);
      slog[r][j] = ev;
      sm[r] += ev;
    }
  }
  #pragma unroll
  for (int r = 0; r < 8; ++r) {
    #pragma unroll
    for (int off = 32; off > 0; off >>= 1) sm[r] += __shfl_xor(sm[r], off, 64);
  }
  __syncthreads();  // all reads of swred (max) done before reuse
  if (lane == 0) {
    #pragma unroll
    for (int r = 0; r < 8; ++r) swred[wv][r] = sm[r];
  }
  __syncthreads();
  float inv[8];
  #pragma unroll
  for (int r = 0; r < 8; ++r)
    inv[r] = 1.f / (swred[0][r] + swred[1][r] + swred[2][r] + swred[3][r]);

  for (int it = 0; it < 16; ++it) {
    const int j = it * 256 + tid;
    #pragma unroll
    for (int r = 0; r < 8; ++r)
      S[(n0 + r) * 4096 + j] = (bf16)(slog[r][j] * inv[r]);
  }
}

// ---- Xt[b*64+c][m] = bf16(x[b][m][c])  (64x64 fp32 tile via LDS) ----
__global__ __launch_bounds__(256) void xpose_x_k(const float* __restrict__ x, bf16* __restrict__ Xt) {
  __shared__ float tile[64][65];
  const int tid = threadIdx.x;
  const int mt = blockIdx.x, b = blockIdx.y;
  const float* src = x + (b * 4096 + mt * 64) * 64;
  #pragma unroll
  for (int it = 0; it < 16; ++it) {
    const int idx = it * 256 + tid;
    tile[idx >> 6][idx & 63] = src[idx];  // idx = m_local*64 + c, coalesced
  }
  __syncthreads();
  #pragma unroll
  for (int it = 0; it < 16; ++it) {
    const int idx = it * 256 + tid;
    const int rr = idx >> 6, cc = idx & 63;  // rr = c (out row), cc = m_local (out col)
    Xt[(b * 64 + rr) * 4096 + mt * 64 + cc] = (bf16)tile[cc][rr];
  }
}

// ---- bf16 4096x4096 transpose: outT[j][i] = in[i][j]  (fallback if ws too small) ----
__global__ __launch_bounds__(256) void transpose_bf16_k(const bf16* __restrict__ in, bf16* __restrict__ outT) {
  __shared__ bf16 tile[64][65];
  const int tid = threadIdx.x;
  const int ti = blockIdx.x & 63, tj = blockIdx.x >> 6;
  #pragma unroll
  for (int it = 0; it < 16; ++it) {
    const int idx = it * 256 + tid;
    tile[idx >> 6][idx & 63] = in[(ti * 64 + (idx >> 6)) * 4096 + tj * 64 + (idx & 63)];
  }
  __syncthreads();
  #pragma unroll
  for (int it = 0; it < 16; ++it) {
    const int idx = it * 256 + tid;
    const int rr = idx >> 6, cc = idx & 63;
    outT[(tj * 64 + rr) * 4096 + ti * 64 + cc] = tile[cc][rr];
  }
}

// ---- C[n][bc] = A[n][:] . Bt[bc][:]  (4096^3, both operands K-contig row-major) ----
// Round-3 schedule. Chunk swizzle phys16Bchunk(row,c)=c^((row>>1)&3) on global
// source + ds_read offset (0 conflicts, round-2 PMC).
// If xmix != nullptr: fused mix epilogue — per wave, b = tn*4+wn, n-rows =
// rowBase+wm128..+127. acc (XG2 slice) -> wave-private LDS stash (As/Bs reuse
// after one barrier), then out[b][n][o] = bias[o] + Acat[n][:] . Wcat[o][:]
// with Acat chunks {x cvt | XG1 | stash}. C/Ct writes skipped in mix mode.
__global__ __launch_bounds__(512, 2) void gemm256_k(const bf16* __restrict__ A,
                                                    const bf16* __restrict__ Bt,
                                                    bf16* __restrict__ C,
                                                    bf16* __restrict__ Ct,
                                                    const float* __restrict__ xmix,
                                                    const bf16* __restrict__ Wc,
                                                    const float* __restrict__ bias,
                                                    float* __restrict__ out) {
  __shared__ bf16 As[2][2][256][32];  // [buf][ks][row][k'] : 64 KiB
  __shared__ bf16 Bs[2][2][256][32];  // 64 KiB
  __shared__ bf16 sW[64 * 200];       // Wcat stage (mix mode): 25.6 KiB; total 156.7 KiB

  const int tid = threadIdx.x;
  const int bid = blockIdx.x;
  const int wg = (bid & 7) * 32 + (bid >> 3);  // XCD swizzle, 256 % 8 == 0 -> bijective
  const int tm = wg >> 4, tn = wg & 15;
  const int rowBase = tm * 256, colBase = tn * 256;

  const int wv = tid >> 6, lane = tid & 63;
  const int wm = wv >> 2, wn = wv & 3;
  const int t16 = lane & 15, quad = lane >> 4;
  const int wv16 = wv * 16;
  const int q8 = (quad ^ ((t16 >> 1) & 3)) * 8;  // swizzled phys chunk for ds_read
  const int wm128 = wm * 128;
  const int wn64 = wn * 64;

  if (xmix) {  // stage Wcat: 512 threads x 24 elems (3 x bf16x8)
    const int rw = tid >> 3, part = tid & 7;
    #pragma unroll
    for (int v = 0; v < 3; ++v)
      *(bf16x8*)(sW + rw * 200 + part * 24 + v * 8) = *(const bf16x8*)(Wc + rw * 192 + part * 24 + v * 8);
  }

  const int sr = tid >> 2;
  const int sc = ((tid & 3) ^ ((tid >> 3) & 3)) * 8;
  const bf16* gA = A + (size_t)(rowBase + sr) * 4096 + sc;
  const bf16* gB = Bt + (size_t)(colBase + sr) * 4096 + sc;

  f32x4 acc[8][4];
  #pragma unroll
  for (int i = 0; i < 8; ++i)
    #pragma unroll
    for (int j = 0; j < 4; ++j) acc[i][j] = (f32x4){0.f, 0.f, 0.f, 0.f};

  auto stA = [&](int buf, int s, int k0) {
    async_lds16(gA + k0 + s * 32, &As[buf][s][wv16][0]);
    async_lds16(gA + 524288 + k0 + s * 32, &As[buf][s][128 + wv16][0]);
  };
  auto stB = [&](int buf, int s, int k0) {
    async_lds16(gB + k0 + s * 32, &Bs[buf][s][wv16][0]);
    async_lds16(gB + 524288 + k0 + s * 32, &Bs[buf][s][128 + wv16][0]);
  };

  bf16x8 Ra[4], Rb[4], B0[4], B1[4];
  auto rdA = [&](bf16x8* R, int buf, int s, int g) {
    #pragma unroll
    for (int i = 0; i < 4; ++i)
      R[i] = *(const bf16x8*)&As[buf][s][wm128 + (g * 4 + i) * 16 + t16][q8];
  };
  auto rdB = [&](bf16x8* R, int buf, int s) {
    #pragma unroll
    for (int j = 0; j < 4; ++j)
      R[j] = *(const bf16x8*)&Bs[buf][s][wn64 + j * 16 + t16][q8];
  };
  auto mfma16 = [&](int g, const bf16x8* R, const bf16x8* Bv) {
    __builtin_amdgcn_s_setprio(1);
    #pragma unroll
    for (int i = 0; i < 4; ++i)
      #pragma unroll
      for (int j = 0; j < 4; ++j)
        acc[g * 4 + i][j] =
            __builtin_amdgcn_mfma_f32_16x16x32_bf16(R[i], Bv[j], acc[g * 4 + i][j], 0, 0, 0);
    __builtin_amdgcn_s_setprio(0);
  };

  // prologue: t0 -> buf0 (4 halves, 8 loads), t1 -> buf1 (3 halves, 6 loads)
  stB(0, 0, 0); stA(0, 0, 0); stB(0, 1, 0); stA(0, 1, 0);
  stB(1, 0, 64); stA(1, 0, 64); stB(1, 1, 64);
  WAIT_VM(6);  // t0 fully landed; t1's 3 halves stay in flight
  BAR();

  for (int it = 0; it < 31; ++it) {
    const int kb = it * 128;
    // R1: buf-switch reads (same-region consume of Ra/B0) + lookahead Rb
    rdA(Ra, 0, 0, 0); rdB(B0, 0, 0); rdA(Rb, 0, 0, 1);
    stA(1, 1, kb + 64);
    mfma16(0, Ra, B0);
    BAR();
    // R2
    rdA(Ra, 0, 1, 0); rdB(B1, 0, 1);
    stB(0, 0, kb + 128);
    mfma16(1, Rb, B0);
    BAR();
    // R3
    rdA(Rb, 0, 1, 1);
    stA(0, 0, kb + 128);
    mfma16(0, Ra, B1);
    BAR();
    // R4: counted wait -> buf1 (t_{2it+1}) fully landed after this barrier
    stB(0, 1, kb + 128);
    mfma16(1, Rb, B1);
    WAIT_VM(6);
    BAR();
    // R5: buf-switch reads of buf1 + lookahead
    rdA(Ra, 1, 0, 0); rdB(B0, 1, 0); rdA(Rb, 1, 0, 1);
    stA(0, 1, kb + 128);
    mfma16(0, Ra, B0);
    BAR();
    // R6
    rdA(Ra, 1, 1, 0); rdB(B1, 1, 1);
    stB(1, 0, kb + 192);
    mfma16(1, Rb, B0);
    BAR();
    // R7
    rdA(Rb, 1, 1, 1);
    stA(1, 0, kb + 192);
    mfma16(0, Ra, B1);
    BAR();
    // R8: counted wait -> buf0 (t_{2it+2}) fully landed after this barrier
    stB(1, 1, kb + 192);
    mfma16(1, Rb, B1);
    WAIT_VM(6);
    BAR();
  }

  // epilogue: tiles 62 (buf0) and 63 (buf1); only remaining stage is t63.Aks1
  rdA(Ra, 0, 0, 0); rdB(B0, 0, 0); rdA(Rb, 0, 0, 1);
  stA(1, 1, 4032);
  mfma16(0, Ra, B0);
  BAR();
  rdA(Ra, 0, 1, 0); rdB(B1, 0, 1);
  mfma16(1, Rb, B0);
  BAR();
  rdA(Rb, 0, 1, 1);
  mfma16(0, Ra, B1);
  BAR();
  mfma16(1, Rb, B1);
  WAIT_VM(0);  // drain: t63 fully landed
  BAR();
  rdA(Ra, 1, 0, 0); rdB(B0, 1, 0); rdA(Rb, 1, 0, 1);
  mfma16(0, Ra, B0);
  rdA(Ra, 1, 1, 0); rdB(B1, 1, 1);
  mfma16(1, Rb, B0);
  rdA(Rb, 1, 1, 1);
  mfma16(0, Ra, B1);
  mfma16(1, Rb, B1);

  if (!xmix) {
    // D: row = quad*4+rr (M dim), col = t16 (N dim)
    #pragma unroll
    for (int i = 0; i < 8; ++i) {
      const int row0 = rowBase + wm128 + i * 16 + quad * 4;
      #pragma unroll
      for (int j = 0; j < 4; ++j) {
        const int col = colBase + wn64 + j * 16 + t16;
        #pragma unroll
        for (int rr = 0; rr < 4; ++rr)
          C[(size_t)(row0 + rr) * 4096 + col] = (bf16)acc[i][j][rr];
      }
    }
    if (Ct) {  // transposed store: Ct[col][row], 4 contiguous bf16 (8B) per frag
      #pragma unroll
      for (int i = 0; i < 8; ++i) {
        const int row0 = rowBase + wm128 + i * 16 + quad * 4;
        #pragma unroll
        for (int j = 0; j < 4; ++j) {
          const int col = colBase + wn64 + j * 16 + t16;
          union { bf16 h[4]; uint2 u; } pk;
          #pragma unroll
          for (int rr = 0; rr < 4; ++rr) pk.h[rr] = (bf16)acc[i][j][rr];
          *(uint2*)(Ct + (size_t)col * 4096 + row0) = pk.u;
        }
      }
    }
    return;
  }

  // ======== fused mix epilogue (GEMM2) ========
  BAR();  // all waves' main-loop LDS reads complete before stash overwrite
  bf16* stash = (wv < 4) ? ((bf16*)As + wv * 8192) : ((bf16*)Bs + (wv - 4) * 8192);
  // acc -> stash[128][64], chunk-XOR key = row&7 (8-elem chunks)
  #pragma unroll
  for (int i = 0; i < 8; ++i) {
    #pragma unroll
    for (int j = 0; j < 4; ++j) {
      #pragma unroll
      for (int rr = 0; rr < 4; ++rr) {
        const int row = i * 16 + quad * 4 + rr;
        const int lc = j * 2 + (t16 >> 3);  // logical 8-elem chunk of col j*16+t16
        stash[row * 64 + ((lc ^ (row & 7)) * 8) + (t16 & 7)] = (bf16)acc[i][j][rr];
      }
    }
  }
  // wave-private from here: no further barriers needed
  const int b = tn * 4 + wn;          // this wave's batch
  const int nrow0 = rowBase + wm128;  // this wave's global n base

  f32x4 macc[8][4];
  #pragma unroll
  for (int i = 0; i < 8; ++i)
    #pragma unroll
    for (int j = 0; j < 4; ++j) macc[i][j] = (f32x4){0.f, 0.f, 0.f, 0.f};

  #pragma unroll
  for (int ch = 0; ch < 6; ++ch) {
    bf16x8 wf[4];
    #pragma unroll
    for (int j = 0; j < 4; ++j)
      wf[j] = *(const bf16x8*)(sW + (j * 16 + t16) * 200 + ch * 32 + quad * 8);
    #pragma unroll
    for (int h = 0; h < 2; ++h) {
      bf16x8 a4[4];
      #pragma unroll
      for (int ii = 0; ii < 4; ++ii) {
        const int i = h * 4 + ii;
        const int rl = i * 16 + t16;         // local n row 0..127
        const int rg = nrow0 + rl;           // global n row
        if (ch < 2) {
          const float* p = xmix + ((size_t)(b * 4096 + rg)) * 64 + ch * 32 + quad * 8;
          float4 f0 = *(const float4*)p;
          float4 f1 = *(const float4*)(p + 4);
          bf16x8 t;
          t[0] = (bf16)f0.x; t[1] = (bf16)f0.y; t[2] = (bf16)f0.z; t[3] = (bf16)f0.w;
          t[4] = (bf16)f1.x; t[5] = (bf16)f1.y; t[6] = (bf16)f1.z; t[7] = (bf16)f1.w;
          a4[ii] = t;
        } else if (ch < 4) {
          a4[ii] = *(const bf16x8*)(C /*=XG1*/ + (size_t)rg * 4096 + b * 64 + (ch & 1) * 32 + quad * 8);
        } else {
          const int c = (ch & 1) * 4 + quad;
          a4[ii] = *(const bf16x8*)(stash + rl * 64 + ((c ^ (rl & 7)) * 8));
        }
      }
      #pragma unroll
      for (int j = 0; j < 4; ++j)
        #pragma unroll
        for (int ii = 0; ii < 4; ++ii)
          macc[h * 4 + ii][j] =
              __builtin_amdgcn_mfma_f32_16x16x32_bf16(a4[ii], wf[j], macc[h * 4 + ii][j], 0, 0, 0);
    }
  }

  #pragma unroll
  for (int j = 0; j < 4; ++j) {
    const float bb = bias[j * 16 + t16];
    #pragma unroll
    for (int i = 0; i < 8; ++i) {
      const int n0 = nrow0 + i * 16 + quad * 4;
      #pragma unroll
      for (int rr = 0; rr < 4; ++rr)
        out[((size_t)(b * 4096 + n0 + rr)) * 64 + j * 16 + t16] = macc[i][j][rr] + bb;
    }
  }
}

extern "C" void kernel_launch(void* const* d_in, const int* in_sizes, int n_in,
                              void* d_out, int out_size, void* d_ws, size_t ws_size,
                              hipStream_t stream) {
  const float* x    = (const float*)d_in[0];  // [64,4096,64]
  const float* adj  = (const float*)d_in[1];  // [4096,16]
  const float* emb  = (const float*)d_in[2];  // [16,4096]
  const float* w    = (const float*)d_in[3];  // [3,64,64]
  const float* bias = (const float*)d_in[4];  // [64]
  float* out = (float*)d_out;

  char* ws = (char*)d_ws;
  const size_t SZ = (size_t)4096 * 4096 * sizeof(bf16);  // 32 MiB
  bf16* S    = (bf16*)(ws);            // [n][m]
  bf16* XG1  = (bf16*)(ws + SZ);       // [n][bc]
  bf16* XBUF = (bf16*)(ws + 3 * SZ);   // Xt [bc][m] (and XG1t fallback)
  const bool fused_t = ws_size >= 5 * SZ + (size_t)(64 * 192 * sizeof(bf16));
  bf16* XG1T = fused_t ? (bf16*)(ws + 4 * SZ) : XBUF;  // [bc][m]
  bf16* Wc   = (bf16*)(ws + (fused_t ? 5 : 4) * SZ);   // [64][192]

  build_wcat_k<<<48, 256, 0, stream>>>(w, Wc);
  supports_k<<<512, 256, 0, stream>>>(adj, emb, S);
  xpose_x_k<<<dim3(64, 64), 256, 0, stream>>>(x, XBUF);
  gemm256_k<<<256, 512, 0, stream>>>(S, XBUF, XG1, fused_t ? XG1T : nullptr,
                                     nullptr, nullptr, nullptr, nullptr);     // XG1 = S @ x
  if (!fused_t) transpose_bf16_k<<<4096, 256, 0, stream>>>(XG1, XBUF);        // XG1t
  // GEMM2 + fused mix: XG2 never materialized; C arg carries XG1 for the mix reads
  gemm256_k<<<256, 512, 0, stream>>>(S, XG1T, XG1, nullptr,
                                     x, Wc, bias, out);
}